// Round 1
// baseline (309.692 us; speedup 1.0000x reference)
//
#include <hip/hip_runtime.h>
#include <math.h>

// Problem constants (from reference)
#define B      512
#define DF     2048
#define DA     312
#define NTHR   320   // 5 waves; threads 0..311 each own one output column
#define RT     8     // rows per block tile in the GEMM
#define KSPLIT 16    // k-split factor (grid.y)
#define NRG    (B / RT)   // 64 row groups

// ---------------------------------------------------------------------------
// Wave (64-lane) reduction helpers
// ---------------------------------------------------------------------------
__device__ __forceinline__ float wave_max_f(float v) {
  #pragma unroll
  for (int off = 32; off >= 1; off >>= 1)
    v = fmaxf(v, __shfl_down(v, off));
  return v;
}

__device__ __forceinline__ double wave_sum_d(double v) {
  #pragma unroll
  for (int off = 32; off >= 1; off >>= 1)
    v += __shfl_down(v, off);
  return v;
}

// ---------------------------------------------------------------------------
// Single fused kernel, split-K atomic-fixup chaining:
//   Phase A (all 1024 blocks): split-K GEMM partials -> part (layout
//     [rg][p][r][c], fully coalesced writes).
//   Phase B (last block per row-group, via device-scope ticket): reduce the
//     16 partials + bias, compute S_row = sum(pre) - DA*(max + log sum exp)
//     in double for 8 rows. Partials are LLC-warm (just written).
//   Phase C (last of the 64 phase-B blocks, via second ticket): pair
//     reduce loss = mean_{i<j, lbl_i==lbl_j} (S_j - S_i).
// No spin-waits anywhere -> forward-progress-safe regardless of scheduling.
// Cross-XCD visibility: __threadfence() (agent release/acquire) around the
// device-scope atomicAdd tickets (Guideline 16). Summation order of partials
// is fixed p=0..ksplit-1, so the result is independent of which block is last.
// ---------------------------------------------------------------------------
__global__ __launch_bounds__(NTHR) void fused_kernel(
    const float* __restrict__ x_f, const float* __restrict__ W,
    const float* __restrict__ b, const int* __restrict__ labels,
    float* __restrict__ part, double* __restrict__ S,
    int* counters, float* __restrict__ out,
    int ksplit, int KC) {
  const int c    = threadIdx.x;
  const int rg   = blockIdx.x;   // row group
  const int ks   = blockIdx.y;   // k chunk
  const int row0 = rg * RT;
  const int k0   = ks * KC;

  __shared__ int       ticket_sh;
  __shared__ float     red_f[8];
  __shared__ float     bcast_max;
  __shared__ double    red_d[16];
  __shared__ long long red_i[8];
  __shared__ double    Ss[B];
  __shared__ int       Ls[B];

  // ---- Phase A: split-K GEMM partial (identical math to previous K1) ----
  if (c < DA) {
    float acc[RT];
    #pragma unroll
    for (int r = 0; r < RT; ++r) acc[r] = 0.f;

    const float* Wp = W + (size_t)k0 * DA + c;
    const float* xp = x_f + (size_t)row0 * DF + k0;

    for (int k = 0; k < KC; k += 8) {
      float w[8];
      #pragma unroll
      for (int j = 0; j < 8; ++j) w[j] = Wp[(size_t)(k + j) * DA];
      #pragma unroll
      for (int r = 0; r < RT; ++r) {
        const float* xr = xp + (size_t)r * DF + k;  // wave-uniform -> s_load
        #pragma unroll
        for (int j = 0; j < 8; ++j) acc[r] = fmaf(xr[j], w[j], acc[r]);
      }
    }

    float* pp = part + (size_t)(rg * ksplit + ks) * RT * DA + c;
    #pragma unroll
    for (int r = 0; r < RT; ++r) pp[(size_t)r * DA] = acc[r];
  }

  __threadfence();                              // release partials (agent scope)
  if (threadIdx.x == 0)
    ticket_sh = atomicAdd(&counters[rg], 1);    // device-scope by default
  __syncthreads();
  if (ticket_sh != ksplit - 1) return;          // not last k-block of this group
  __threadfence();                              // acquire other blocks' partials

  // ---- Phase B: row stats for rows row0..row0+RT-1 ----
  const int wid  = threadIdx.x >> 6;
  const int lane = threadIdx.x & 63;

  float s[RT];
  if (c < DA) {
    const float bias = b[c];
    #pragma unroll
    for (int r = 0; r < RT; ++r) s[r] = bias;
    const float* pb = part + (size_t)rg * ksplit * RT * DA + c;
    for (int p = 0; p < ksplit; ++p) {          // fixed order -> deterministic
      #pragma unroll
      for (int r = 0; r < RT; ++r)
        s[r] += pb[((size_t)p * RT + r) * DA];
    }
  }

  for (int r = 0; r < RT; ++r) {
    float v = (c < DA) ? s[r] : -INFINITY;
    float m = wave_max_f(v);
    if (lane == 0) red_f[wid] = m;
    __syncthreads();
    if (threadIdx.x == 0) {
      float mm = red_f[0];
      #pragma unroll
      for (int w = 1; w < NTHR / 64; ++w) mm = fmaxf(mm, red_f[w]);
      bcast_max = mm;
    }
    __syncthreads();
    const float rowmax = bcast_max;

    double e  = (c < DA) ? exp((double)v - (double)rowmax) : 0.0;
    double sp = (c < DA) ? (double)v : 0.0;
    double es = wave_sum_d(e);
    double ss = wave_sum_d(sp);
    if (lane == 0) { red_d[wid] = es; red_d[8 + wid] = ss; }
    __syncthreads();
    if (threadIdx.x == 0) {
      double esum = 0.0, ssum = 0.0;
      #pragma unroll
      for (int w = 0; w < NTHR / 64; ++w) { esum += red_d[w]; ssum += red_d[8 + w]; }
      S[row0 + r] = ssum - (double)DA * ((double)rowmax + log(esum));
    }
    __syncthreads();   // protect red_f/red_d reuse next round
  }

  __threadfence();                              // release S rows
  if (threadIdx.x == 0)
    ticket_sh = atomicAdd(&counters[NRG], 1);
  __syncthreads();
  if (ticket_sh != NRG - 1) return;             // not the last row-group fixup
  __threadfence();                              // acquire all S

  // ---- Phase C: pair reduce (single block, 320 threads, exact double) ----
  for (int i = threadIdx.x; i < B; i += NTHR) { Ss[i] = S[i]; Ls[i] = labels[i]; }
  __syncthreads();

  double lsum = 0.0;
  long long lcnt = 0;
  for (int p = threadIdx.x; p < B * B; p += NTHR) {
    int i = p >> 9;          // p / 512
    int j = p & (B - 1);     // p % 512
    if (j > i && Ls[i] == Ls[j]) { lsum += Ss[j] - Ss[i]; lcnt++; }
  }
  #pragma unroll
  for (int off = 32; off >= 1; off >>= 1) {
    lsum += __shfl_down(lsum, off);
    lcnt += __shfl_down(lcnt, off);
  }
  if (lane == 0) { red_d[wid] = lsum; red_i[wid] = lcnt; }
  __syncthreads();
  if (threadIdx.x == 0) {
    double s2 = 0.0; long long c2 = 0;
    #pragma unroll
    for (int w = 0; w < NTHR / 64; ++w) { s2 += red_d[w]; c2 += red_i[w]; }
    out[0] = (float)((c2 > 0) ? s2 / (double)c2 : s2);
  }
}

// ---------------------------------------------------------------------------
extern "C" void kernel_launch(void* const* d_in, const int* in_sizes, int n_in,
                              void* d_out, int out_size, void* d_ws, size_t ws_size,
                              hipStream_t stream) {
  const float* x_f    = (const float*)d_in[0];   // [B, DF]
  const float* W      = (const float*)d_in[1];   // [DF, DA]
  const float* b      = (const float*)d_in[2];   // [DA]
  // d_in[3] = seen_att: cancels exactly for same-label pairs (unused)
  const int*   labels = (const int*)d_in[4];     // [B]

  // ws layout: [ counters: 65 ints (512B) ][ S: B doubles ][ pad to 8K ][ part ]
  int ksplit = KSPLIT;
  size_t need = 8192 + (size_t)KSPLIT * B * DA * 4;
  if (ws_size < need) ksplit = 2;                // tiny-ws fallback

  int*    counters = (int*)d_ws;
  double* S        = (double*)((char*)d_ws + 512);
  float*  part     = (float*)((char*)d_ws + 8192);
  const int KC = DF / ksplit;

  hipMemsetAsync(d_ws, 0, 512, stream);          // zero tickets (ws is poisoned)
  dim3 g(NRG, ksplit);
  fused_kernel<<<g, NTHR, 0, stream>>>(x_f, W, b, labels, part, S, counters,
                                       (float*)d_out, ksplit, KC);
}

// Round 2
// 112.694 us; speedup vs baseline: 2.7481x; 2.7481x over previous
//
#include <hip/hip_runtime.h>
#include <math.h>

// Problem constants (from reference)
#define B      512
#define DF     2048
#define DA     312
#define NTHR   320   // 5 waves; threads 0..311 each own one output column
#define RT     8     // rows per block tile in the GEMM
#define KSPLIT 16    // k-split factor (grid.y)
#define NRG    (B / RT)   // 64 row groups

// ---------------------------------------------------------------------------
// Wave (64-lane) reduction helpers
// ---------------------------------------------------------------------------
__device__ __forceinline__ float wave_max_f(float v) {
  #pragma unroll
  for (int off = 32; off >= 1; off >>= 1)
    v = fmaxf(v, __shfl_down(v, off));
  return v;
}

__device__ __forceinline__ double wave_sum_d(double v) {
  #pragma unroll
  for (int off = 32; off >= 1; off >>= 1)
    v += __shfl_down(v, off);
  return v;
}

// ---------------------------------------------------------------------------
// K1: split-K GEMM partials, NO LDS. KC is a COMPILE-TIME constant so the
// 16-octet k-loop fully unrolls; explicit next-octet W prefetch lets the
// loads of octet k+1 fly while the FMAs of octet k issue (no per-octet
// exposed L2 latency). Thread c owns one output column: W reads are
// lane-contiguous coalesced dwords; x reads are wave-uniform -> s_load.
// Partial layout: [rg][ks][r][c] (contiguous 8x312 block per (rg,ks)) so K2
// gathers from a single 160 KB window per row-group.
// ---------------------------------------------------------------------------
template <int KC>
__global__ __launch_bounds__(NTHR, 5) void gemm_partial_kernel(
    const float* __restrict__ x_f, const float* __restrict__ W,
    float* __restrict__ part) {
  const int c    = threadIdx.x;
  const int rg   = blockIdx.x;
  const int ks   = blockIdx.y;
  const int row0 = rg * RT;
  const int k0   = ks * KC;
  const int ksplit = DF / KC;

  if (c >= DA) return;

  float acc[RT];
  #pragma unroll
  for (int r = 0; r < RT; ++r) acc[r] = 0.f;

  const float* Wp = W + (size_t)k0 * DA + c;
  const float* xp = x_f + (size_t)row0 * DF + k0;

  float wc[8];
  #pragma unroll
  for (int j = 0; j < 8; ++j) wc[j] = Wp[(size_t)j * DA];

  #pragma unroll
  for (int k = 0; k < KC; k += 8) {
    float wn[8];
    if (k + 8 < KC) {                    // prefetch next octet of W
      #pragma unroll
      for (int j = 0; j < 8; ++j) wn[j] = Wp[(size_t)(k + 8 + j) * DA];
    }
    #pragma unroll
    for (int r = 0; r < RT; ++r) {
      const float* xr = xp + (size_t)r * DF + k;  // wave-uniform -> s_load
      #pragma unroll
      for (int j = 0; j < 8; ++j) acc[r] = fmaf(xr[j], wc[j], acc[r]);
    }
    if (k + 8 < KC) {
      #pragma unroll
      for (int j = 0; j < 8; ++j) wc[j] = wn[j];
    }
  }

  float* pp = part + ((size_t)(rg * ksplit + ks) * RT) * DA + c;
  #pragma unroll
  for (int r = 0; r < RT; ++r) pp[(size_t)r * DA] = acc[r];
}

// ---------------------------------------------------------------------------
// K2: per-row reduce partials + bias, then
//     S_i = sum_d pre - DA*(max + log(sum exp(pre-max)))   (double accum)
// One block per row, 320 threads, thread c owns column c. All KS partial
// loads issued before the sum (ILP); summation order fixed p=0..KS-1.
// ---------------------------------------------------------------------------
template <int KS>
__global__ __launch_bounds__(NTHR) void row_stats_kernel(
    const float* __restrict__ part, const float* __restrict__ b,
    double* __restrict__ S) {
  __shared__ float  red_f[8];
  __shared__ double red_d[16];
  __shared__ float  bcast_max;

  const int tid  = threadIdx.x;
  const int wid  = tid >> 6;
  const int lane = tid & 63;
  const int row  = blockIdx.x;
  const int rg   = row / RT;
  const int r    = row & (RT - 1);

  float v = -INFINITY;
  if (tid < DA) {
    const float* pb = part + ((size_t)(rg * KS) * RT + r) * DA + tid;
    float ps[KS];
    #pragma unroll
    for (int p = 0; p < KS; ++p) ps[p] = pb[(size_t)p * RT * DA];
    float s = b[tid];
    #pragma unroll
    for (int p = 0; p < KS; ++p) s += ps[p];
    v = s;
  }

  // block max
  float m = wave_max_f(v);
  if (lane == 0) red_f[wid] = m;
  __syncthreads();
  if (tid == 0) {
    float mm = red_f[0];
    #pragma unroll
    for (int w = 1; w < NTHR / 64; ++w) mm = fmaxf(mm, red_f[w]);
    bcast_max = mm;
  }
  __syncthreads();
  const float rowmax = bcast_max;

  // double-precision sums: exp(v - max) and raw v
  double e  = (tid < DA) ? exp((double)v - (double)rowmax) : 0.0;
  double sp = (tid < DA) ? (double)v : 0.0;
  double es = wave_sum_d(e);
  double ss = wave_sum_d(sp);
  if (lane == 0) { red_d[wid] = es; red_d[8 + wid] = ss; }
  __syncthreads();
  if (tid == 0) {
    double esum = 0.0, ssum = 0.0;
    #pragma unroll
    for (int w = 0; w < NTHR / 64; ++w) { esum += red_d[w]; ssum += red_d[8 + w]; }
    S[row] = ssum - (double)DA * ((double)rowmax + log(esum));
  }
}

// ---------------------------------------------------------------------------
// K3: loss = sum_{i<j, lbl_i==lbl_j} (S_j - S_i) / count
// One block, 1024 threads; S and labels cached in LDS. Exact (double).
// ---------------------------------------------------------------------------
__global__ __launch_bounds__(1024) void pair_reduce_kernel(
    const double* __restrict__ S, const int* __restrict__ labels,
    float* __restrict__ out) {
  __shared__ double    Ss[B];
  __shared__ int       Ls[B];
  __shared__ double    red_d[16];
  __shared__ long long red_i[16];

  const int tid = threadIdx.x;
  if (tid < B) { Ss[tid] = S[tid]; Ls[tid] = labels[tid]; }
  __syncthreads();

  double lsum = 0.0;
  long long lcnt = 0;
  for (int p = tid; p < B * B; p += 1024) {
    int i = p >> 9;          // p / 512
    int j = p & (B - 1);     // p % 512
    if (j > i && Ls[i] == Ls[j]) { lsum += Ss[j] - Ss[i]; lcnt++; }
  }

  #pragma unroll
  for (int off = 32; off >= 1; off >>= 1) {
    lsum += __shfl_down(lsum, off);
    lcnt += __shfl_down(lcnt, off);
  }
  const int wid = tid >> 6, lane = tid & 63;
  if (lane == 0) { red_d[wid] = lsum; red_i[wid] = lcnt; }
  __syncthreads();
  if (tid == 0) {
    double s = 0.0; long long c = 0;
    #pragma unroll
    for (int w = 0; w < 16; ++w) { s += red_d[w]; c += red_i[w]; }
    out[0] = (float)((c > 0) ? s / (double)c : s);
  }
}

// ---------------------------------------------------------------------------
extern "C" void kernel_launch(void* const* d_in, const int* in_sizes, int n_in,
                              void* d_out, int out_size, void* d_ws, size_t ws_size,
                              hipStream_t stream) {
  const float* x_f    = (const float*)d_in[0];   // [B, DF]
  const float* W      = (const float*)d_in[1];   // [DF, DA]
  const float* b      = (const float*)d_in[2];   // [DA]
  // d_in[3] = seen_att: cancels exactly for same-label pairs (unused)
  const int*   labels = (const int*)d_in[4];     // [B]

  // ws layout: [ S: B doubles (4 KB) ][ part: ksplit*B*DA floats ]
  double* S    = (double*)d_ws;
  float*  part = (float*)((char*)d_ws + 4096);

  if (ws_size >= 4096 + (size_t)KSPLIT * B * DA * 4) {
    dim3 g1(NRG, KSPLIT);
    gemm_partial_kernel<DF / KSPLIT><<<g1, NTHR, 0, stream>>>(x_f, W, part);
    row_stats_kernel<KSPLIT><<<B, NTHR, 0, stream>>>(part, b, S);
  } else {                                       // tiny-ws fallback
    dim3 g1(NRG, 2);
    gemm_partial_kernel<DF / 2><<<g1, NTHR, 0, stream>>>(x_f, W, part);
    row_stats_kernel<2><<<B, NTHR, 0, stream>>>(part, b, S);
  }
  pair_reduce_kernel<<<1, 1024, 0, stream>>>(S, labels, (float*)d_out);
}